// Round 3
// baseline (974.876 us; speedup 1.0000x reference)
//
#include <hip/hip_runtime.h>

#define NLEVELS 16
#define HSIZE (1u << 19)
#define HMASK ((1u << 19) - 1u)
#define P2 73856093u
#define P3 19349663u

// res[L] = floor(16 * (2^(1/3))^L) — compile-time so unrolled levels fold to immediates
constexpr int RES[NLEVELS] = {16, 20, 25, 32, 40, 50, 64, 80,
                              101, 128, 161, 203, 256, 322, 406, 512};

// One level's trilinear hash-encode. L is compile-time (full unroll) so the
// table base and res are immediates; all lanes share one 4 MiB table.
#define DO_LEVEL(L, O0, O1)                                                   \
    do {                                                                      \
        const float2* __restrict__ tab = (const float2*)tables + (size_t)(L) * HSIZE; \
        const float rm1 = (float)(RES[(L)] - 1);                              \
        float sx = px * rm1, sy = py * rm1, sz = pz * rm1;                    \
        float bx = floorf(sx), by = floorf(sy), bz = floorf(sz);              \
        float fx = sx - bx, fy = sy - by, fz = sz - bz;                       \
        unsigned ix = (unsigned)(int)bx, iy = (unsigned)(int)by, iz = (unsigned)(int)bz; \
        unsigned s00 = ix + iy * P2 + iz * P3;                                \
        unsigned h000 = s00 & HMASK,            h100 = (s00 + 1u) & HMASK;    \
        unsigned h010 = (s00 + P2) & HMASK,     h110 = (s00 + P2 + 1u) & HMASK; \
        unsigned h001 = (s00 + P3) & HMASK,     h101 = (s00 + P3 + 1u) & HMASK; \
        unsigned h011 = (s00 + P2 + P3) & HMASK, h111 = (s00 + P2 + P3 + 1u) & HMASK; \
        /* pairs (h,h+1) usually share a 64B line -> L1 catches the partner */ \
        float2 f000 = tab[h000]; float2 f100 = tab[h100];                     \
        float2 f010 = tab[h010]; float2 f110 = tab[h110];                     \
        float2 f001 = tab[h001]; float2 f101 = tab[h101];                     \
        float2 f011 = tab[h011]; float2 f111 = tab[h111];                     \
        float wx0 = 1.0f - fx, wy0 = 1.0f - fy, wz0 = 1.0f - fz;              \
        float w;                                                              \
        w = wx0 * wy0 * wz0; O0 += w * f000.x; O1 += w * f000.y;              \
        w = wx0 * wy0 * fz;  O0 += w * f001.x; O1 += w * f001.y;              \
        w = wx0 * fy * wz0;  O0 += w * f010.x; O1 += w * f010.y;              \
        w = wx0 * fy * fz;   O0 += w * f011.x; O1 += w * f011.y;              \
        w = fx * wy0 * wz0;  O0 += w * f100.x; O1 += w * f100.y;              \
        w = fx * wy0 * fz;   O0 += w * f101.x; O1 += w * f101.y;              \
        w = fx * fy * wz0;   O0 += w * f110.x; O1 += w * f110.y;              \
        w = fx * fy * fz;    O0 += w * f111.x; O1 += w * f111.y;              \
    } while (0)

__global__ __launch_bounds__(256) void hashgrid_kernel(
    const float* __restrict__ positions,  // [npoints, 3]
    const float* __restrict__ tables,     // [16, 2^19, 2]
    float4* __restrict__ out4,            // [npoints * 8] float4 (= [npoints,16] float2)
    int npoints)
{
    int p = blockIdx.x * 256 + threadIdx.x;
    if (p >= npoints) return;

    // position -> [0,1]; read once per point (was 16x)
    float px = (positions[3 * p + 0] + 1.0f) * 0.5f;
    float py = (positions[3 * p + 1] + 1.0f) * 0.5f;
    float pz = (positions[3 * p + 2] + 1.0f) * 0.5f;

    size_t obase = (size_t)p * 8;

    // Two levels per iteration: 16 gathers in flight, then one float4 store.
    // The same thread writes all 4 float4s of each 64B out-line within the
    // loop window, so the writeback L2 merges them into full-line writes.
#pragma unroll
    for (int pair = 0; pair < 8; ++pair) {
        float o0a = 0.0f, o1a = 0.0f, o0b = 0.0f, o1b = 0.0f;
        DO_LEVEL(2 * pair, o0a, o1a);
        DO_LEVEL(2 * pair + 1, o0b, o1b);
        out4[obase + pair] = make_float4(o0a, o1a, o0b, o1b);
    }
}

extern "C" void kernel_launch(void* const* d_in, const int* in_sizes, int n_in,
                              void* d_out, int out_size, void* d_ws, size_t ws_size,
                              hipStream_t stream) {
    const float* positions = (const float*)d_in[0];
    const float* tables = (const float*)d_in[1];
    float4* out4 = (float4*)d_out;
    int npoints = in_sizes[0] / 3;          // 1,048,576
    int blocks = (npoints + 255) / 256;     // 4096 blocks
    hashgrid_kernel<<<blocks, 256, 0, stream>>>(positions, tables, out4, npoints);
}

// Round 4
// 649.724 us; speedup vs baseline: 1.5004x; 1.5004x over previous
//
#include <hip/hip_runtime.h>

#define NLEVELS 16
#define NPOINTS (1u << 20)
#define HSIZE (1u << 19)
#define HMASK ((1u << 19) - 1u)
#define P2 73856093u
#define P3 19349663u
#define BLOCKS_PER_LEVEL 4096   // 4096 * 256 threads = 1,048,576 points

// res[L] = floor(16 * (2^(1/3))^L)
__constant__ int c_res[NLEVELS] = {16, 20, 25, 32, 40, 50, 64, 80,
                                   101, 128, 161, 203, 256, 322, 406, 512};

// ---------------------------------------------------------------------------
// Kernel A: level-major compute with XCD-level affinity.
// MI355X dispatches workgroups round-robin over 8 XCDs (xcd = blockIdx % 8).
// Block b: xcd = b&7, j = b>>3 in [0,8192): level = xcd (j<4096) else xcd+8,
// point chunk = j&4095. Each XCD therefore streams through exactly ONE
// 4 MiB table per phase -> table is L2-resident for the whole phase.
// Output goes to ws in [L][p] layout -> fully coalesced float2 stores.
// ---------------------------------------------------------------------------
template <bool TO_WS>
__global__ __launch_bounds__(256) void hashgrid_kernel(
    const float* __restrict__ positions,  // [npoints, 3]
    const float* __restrict__ tables,     // [16, 2^19, 2]
    float2* __restrict__ dst,             // TO_WS: ws [16][npoints]; else out [npoints][16]
    int npoints)
{
    int b = blockIdx.x;
    int L, chunk;
    if (TO_WS) {
        int xcd = b & 7;
        int j = b >> 3;                       // 0..8191
        L = xcd + ((j >= BLOCKS_PER_LEVEL) ? 8 : 0);
        chunk = j & (BLOCKS_PER_LEVEL - 1);
    } else {
        L = b >> 12;
        chunk = b & (BLOCKS_PER_LEVEL - 1);
    }
    int p = chunk * 256 + threadIdx.x;
    if (p >= npoints) return;

    // position -> [0,1], two rounding steps to match reference exactly
    float px = (positions[3 * p + 0] + 1.0f) * 0.5f;
    float py = (positions[3 * p + 1] + 1.0f) * 0.5f;
    float pz = (positions[3 * p + 2] + 1.0f) * 0.5f;

    float rm1 = (float)(c_res[L] - 1);
    float sx = px * rm1, sy = py * rm1, sz = pz * rm1;
    float bx = floorf(sx), by = floorf(sy), bz = floorf(sz);
    float fx = sx - bx, fy = sy - by, fz = sz - bz;

    unsigned ix = (unsigned)(int)bx;
    unsigned iy = (unsigned)(int)by;
    unsigned iz = (unsigned)(int)bz;

    unsigned s00 = ix + iy * P2 + iz * P3;
    unsigned h000 = s00 & HMASK,             h100 = (s00 + 1u) & HMASK;
    unsigned h010 = (s00 + P2) & HMASK,      h110 = (s00 + P2 + 1u) & HMASK;
    unsigned h001 = (s00 + P3) & HMASK,      h101 = (s00 + P3 + 1u) & HMASK;
    unsigned h011 = (s00 + P2 + P3) & HMASK, h111 = (s00 + P2 + P3 + 1u) & HMASK;

    const float2* __restrict__ tab = (const float2*)tables + (size_t)L * HSIZE;

    // pair order: (h, h+1) usually share a 64B line -> L1 catches the partner
    float2 f000 = tab[h000]; float2 f100 = tab[h100];
    float2 f010 = tab[h010]; float2 f110 = tab[h110];
    float2 f001 = tab[h001]; float2 f101 = tab[h101];
    float2 f011 = tab[h011]; float2 f111 = tab[h111];

    float wx0 = 1.0f - fx, wy0 = 1.0f - fy, wz0 = 1.0f - fz;

    float o0 = 0.0f, o1 = 0.0f, w;
    w = wx0 * wy0 * wz0; o0 += w * f000.x; o1 += w * f000.y;
    w = wx0 * wy0 * fz;  o0 += w * f001.x; o1 += w * f001.y;
    w = wx0 * fy * wz0;  o0 += w * f010.x; o1 += w * f010.y;
    w = wx0 * fy * fz;   o0 += w * f011.x; o1 += w * f011.y;
    w = fx * wy0 * wz0;  o0 += w * f100.x; o1 += w * f100.y;
    w = fx * wy0 * fz;   o0 += w * f101.x; o1 += w * f101.y;
    w = fx * fy * wz0;   o0 += w * f110.x; o1 += w * f110.y;
    w = fx * fy * fz;    o0 += w * f111.x; o1 += w * f111.y;

    if (TO_WS)
        dst[(size_t)L * npoints + p] = make_float2(o0, o1);      // coalesced
    else
        dst[(size_t)p * NLEVELS + L] = make_float2(o0, o1);      // strided (fallback)
}

// ---------------------------------------------------------------------------
// Kernel B: transpose ws [16][npoints] float2 -> out [npoints][16] float2,
// coalesced on both sides via an LDS tile. Block = 256 points.
// ---------------------------------------------------------------------------
__global__ __launch_bounds__(256) void transpose_kernel(
    const float2* __restrict__ ws,   // [16][npoints]
    float4* __restrict__ out4,       // [npoints * 8]
    int npoints)
{
    __shared__ float2 lds[256][NLEVELS + 1];   // +1 pad: 34 KB
    int c = blockIdx.x;
    int t = threadIdx.x;
    int pbase = c * 256;

#pragma unroll
    for (int L = 0; L < NLEVELS; ++L)
        lds[t][L] = ws[(size_t)L * npoints + pbase + t];   // coalesced reads
    __syncthreads();

    size_t obase = (size_t)c * 2048;   // 256 points * 8 float4
#pragma unroll
    for (int k = 0; k < 8; ++k) {
        int i = k * 256 + t;
        int pp = i >> 3;       // point within block
        int q = i & 7;         // level pair
        float2 a = lds[pp][2 * q];
        float2 b = lds[pp][2 * q + 1];
        out4[obase + i] = make_float4(a.x, a.y, b.x, b.y);  // coalesced writes
    }
}

extern "C" void kernel_launch(void* const* d_in, const int* in_sizes, int n_in,
                              void* d_out, int out_size, void* d_ws, size_t ws_size,
                              hipStream_t stream) {
    const float* positions = (const float*)d_in[0];
    const float* tables = (const float*)d_in[1];
    int npoints = in_sizes[0] / 3;                    // 1,048,576
    int blocks = NLEVELS * BLOCKS_PER_LEVEL;          // 65,536

    size_t ws_needed = (size_t)NLEVELS * npoints * sizeof(float2);  // 128 MiB
    if (ws_size >= ws_needed) {
        float2* ws = (float2*)d_ws;
        hashgrid_kernel<true><<<blocks, 256, 0, stream>>>(positions, tables, ws, npoints);
        transpose_kernel<<<(npoints + 255) / 256, 256, 0, stream>>>(ws, (float4*)d_out, npoints);
    } else {
        // fallback: direct strided write (round-2 behavior)
        hashgrid_kernel<false><<<blocks, 256, 0, stream>>>(positions, tables, (float2*)d_out, npoints);
    }
}